// Round 21
// baseline (64.757 us; speedup 1.0000x reference)
//
#include <hip/hip_runtime.h>
#include <hip/hip_bf16.h>
#include <stdint.h>

#define SEQ 4096
#define EMB 1024
#define HD  64
#define NB  4

typedef __attribute__((ext_vector_type(8))) short short8;   // 8 x bf16 (4 VGPRs)
typedef __attribute__((ext_vector_type(4))) float f32x4;
typedef __attribute__((ext_vector_type(4))) unsigned int uint4v;

// RNE float -> bf16 bits (no NaN inputs here)
static __device__ __forceinline__ unsigned short f2bf(float f) {
    unsigned int u = __float_as_uint(f);
    u += 0x7fffu + ((u >> 16) & 1u);
    return (unsigned short)(u >> 16);
}

// ---------------------------------------------------------------------------
// Prep: Wt[m][d][e] = bf16(W_m[e][d]),  m in {q,k,v}.  3*64*1024 elements.
// Wq is pre-scaled by log2(e)/sqrt(64) so attn needs no scale multiply.
// ---------------------------------------------------------------------------
__global__ __launch_bounds__(256) void wprep_kernel(
        const float* __restrict__ Wq, const float* __restrict__ Wk,
        const float* __restrict__ Wv, unsigned short* __restrict__ Wt) {
    int idx = blockIdx.x * 256 + threadIdx.x;       // < 3*65536
    int m = idx >> 16;
    int r = idx & 65535;
    int d = r >> 10;
    int e = r & 1023;
    const float* W = (m == 0) ? Wq : (m == 1) ? Wk : Wv;
    float v = W[e * HD + d];
    if (m == 0) v *= 0.18033688011111793f;          // log2(e)/sqrt(64)
    Wt[idx] = f2bf(v);
}

// ---------------------------------------------------------------------------
// QKV v3 — LDS-cooperative + 3-buffer counted-vmcnt pipeline (unchanged R18).
// ---------------------------------------------------------------------------
__global__ __launch_bounds__(512, 4) void qkv_kernel(
        const float* __restrict__ H, const unsigned short* __restrict__ Wt,
        unsigned short* __restrict__ Qb, unsigned short* __restrict__ Kb,
        unsigned short* __restrict__ Vt) {
    __shared__ unsigned char smem[122880];           // 120 KB: 3 x (24KB W + 16KB H)
    unsigned short* ldsW = (unsigned short*)smem;            // [3][192][64] bf16
    float* ldsH = (float*)(smem + 3 * 24576);                // [3][64][64] f32
    float* ldsO = (float*)smem;                              // epilogue overlay [64][200]

    const int tid  = threadIdx.x;
    const int w    = tid >> 6;
    const int lane = tid & 63;
    const int lr = lane & 15, lg = lane >> 4;
    const int rt = w >> 1, ch = w & 1;
    const int rowbase = blockIdx.x * 64;

    f32x4 acc[6];
    #pragma unroll
    for (int nt = 0; nt < 6; ++nt) acc[nt] = f32x4{0.f, 0.f, 0.f, 0.f};

    auto stage = [&](int buf, int c) {
        const int kk0 = c * 64;
        #pragma unroll
        for (int ii = 0; ii < 3; ++ii) {
            int i = w * 3 + ii;
            int rowidx = 8 * i + (lane >> 3);            // 0..191  (m*64+d)
            int sb = (lane & 7) ^ (lane >> 3);           // src 16B-block ^ (row&7)
            const unsigned short* src = Wt + rowidx * EMB + kk0 + sb * 8;
            __builtin_amdgcn_global_load_lds(
                (const __attribute__((address_space(1))) void*)src,
                (__attribute__((address_space(3))) void*)(ldsW + buf * 12288 + i * 512 + lane * 8),
                16, 0, 0);
        }
        #pragma unroll
        for (int ii = 0; ii < 2; ++ii) {
            int i = w * 2 + ii;
            int rowidx = 4 * i + (lane >> 4);            // 0..63
            int key = rowidx & 7;
            int sb = (lane & 15) ^ key;                  // src 16B-block ^ (row&7)
            const float* src = H + (size_t)(rowbase + rowidx) * EMB + kk0 + sb * 4;
            __builtin_amdgcn_global_load_lds(
                (const __attribute__((address_space(1))) void*)src,
                (__attribute__((address_space(3))) void*)(ldsH + buf * 4096 + i * 256 + lane * 4),
                16, 0, 0);
        }
    };

    auto compute = [&](int buf) {
        const int hrow = rt * 16 + lr;
        const int hkey = lr & 7;
        #pragma unroll
        for (int ks = 0; ks < 2; ++ks) {
            int b0 = ks * 8 + lg * 2;
            f32x4 h0 = *(const f32x4*)(ldsH + buf * 4096 + hrow * 64 + ((b0 ^ hkey) * 4));
            f32x4 h1 = *(const f32x4*)(ldsH + buf * 4096 + hrow * 64 + (((b0 + 1) ^ hkey) * 4));
            uint4v ua;
            asm("v_cvt_pk_bf16_f32 %0, %1, %2" : "=v"(ua[0]) : "v"(h0[0]), "v"(h0[1]));
            asm("v_cvt_pk_bf16_f32 %0, %1, %2" : "=v"(ua[1]) : "v"(h0[2]), "v"(h0[3]));
            asm("v_cvt_pk_bf16_f32 %0, %1, %2" : "=v"(ua[2]) : "v"(h1[0]), "v"(h1[1]));
            asm("v_cvt_pk_bf16_f32 %0, %1, %2" : "=v"(ua[3]) : "v"(h1[2]), "v"(h1[3]));
            short8 af = *(short8*)&ua;
            #pragma unroll
            for (int nt = 0; nt < 6; ++nt) {
                int f = ch * 6 + nt;
                int row = f * 16 + lr;                   // (row&7) == lr&7 == hkey
                int blk = (ks * 4 + lg) ^ hkey;
                short8 bf_ = *(const short8*)(ldsW + buf * 12288 + row * 64 + blk * 8);
                acc[nt] = __builtin_amdgcn_mfma_f32_16x16x32_bf16(af, bf_, acc[nt], 0, 0, 0);
            }
        }
    };

    stage(0, 0);
    stage(1, 1);
    for (int c = 0; c < 16; ++c) {
        if (c + 2 < 16) stage((c + 2) % 3, c + 2);
        if (c <= 13)      asm volatile("s_waitcnt vmcnt(10)" ::: "memory");
        else if (c == 14) asm volatile("s_waitcnt vmcnt(5)"  ::: "memory");
        else              asm volatile("s_waitcnt vmcnt(0)"  ::: "memory");
        __builtin_amdgcn_sched_barrier(0);
        __builtin_amdgcn_s_barrier();
        compute(c % 3);
        __builtin_amdgcn_s_barrier();   // readers of buf c%3 done before reuse
    }

    #pragma unroll
    for (int nt = 0; nt < 6; ++nt)
        #pragma unroll
        for (int r = 0; r < 4; ++r)
            ldsO[(rt * 16 + lg * 4 + r) * 200 + ch * 96 + nt * 16 + lr] = acc[nt][r];
    __syncthreads();

    {   // Q and K: 512 threads, row = tid>>3 (0..63), 8 cols each
        const int row = tid >> 3;
        const int d0  = (tid & 7) * 8;
        const size_t grow = (size_t)(rowbase + row);
        short8 uq, uk;
        #pragma unroll
        for (int j = 0; j < 8; ++j) {
            uq[j] = (short)f2bf(ldsO[row * 200 + d0 + j]);
            uk[j] = (short)f2bf(ldsO[row * 200 + 64 + d0 + j]);
        }
        *(short8*)(Qb + grow * HD + d0) = uq;
        *(short8*)(Kb + grow * HD + (d0 ^ ((row & 7) << 3))) = uk;
    }
    {   // V: block covers exactly one 64-chunk; d = tid>>3, 4 u32 pairs each
        const int d  = tid >> 3;
        const int j  = tid & 7;
        const int b  = rowbase >> 12;
        const int ci = (rowbase & (SEQ - 1)) >> 6;
        unsigned short* vrow = Vt + (((size_t)b * 64 + ci) * 64 + d) * 64;
        const int dsw = (d & 7) << 3;
        #pragma unroll
        for (int k4 = 0; k4 < 4; ++k4) {
            int t0 = j * 2 + k4 * 16;            // even t in 0..62
            int tt = t0 & 31;
            int p0 = ((tt & 12) << 1) | (tt & 3) | ((tt & 16) >> 2);
            int e  = ((t0 & 32) | p0) ^ dsw;
            unsigned int val = (unsigned int)f2bf(ldsO[t0 * 200 + 128 + d])
                             | ((unsigned int)f2bf(ldsO[(t0 + 1) * 200 + 128 + d]) << 16);
            *(unsigned int*)(vrow + e) = val;
        }
    }
}

// ---------------------------------------------------------------------------
// Flash attention v5b: TWO Q-TILES PER BLOCK — identical to R20 EXCEPT
// __launch_bounds__(512, 2): the (512,4) bound capped VGPR at 64 and the
// ~110-VGPR state spilled to scratch (the R20 regression). 128 VGPR now;
// 2 blocks/CU via LDS (48 KB). All else unchanged.
// ---------------------------------------------------------------------------
__global__ __launch_bounds__(512, 2) void attn_kernel(
        const unsigned short* __restrict__ Qb, const unsigned short* __restrict__ Kb,
        const unsigned short* __restrict__ Vt,
        float* __restrict__ part_o, float* __restrict__ part_l) {
    __shared__ unsigned short ldsK[3 * 4096];   // 24 KB (3 bufs, swizzled)
    __shared__ unsigned short ldsV[3 * 4096];   // 24 KB
    const int tid  = threadIdx.x;
    const int w    = tid >> 6;
    const int lane = tid & 63;
    const int lr = lane & 15, lg = lane >> 4;

    const int bid   = blockIdx.x;
    const int b     = bid & 3;
    const int pr    = (bid >> 2) & 15;
    const int slice = bid >> 6;                    // 0..7
    const int p     = (slice >= 4) ? (15 - pr) : pr;   // complementary pairing
    const int qbase = p * 256;
    const int qa0   = qbase + w * 16;              // tile A rows
    const int qb0   = qbase + 128 + w * 16;        // tile B rows

    const unsigned short* __restrict__ Kp = Kb + (size_t)b * SEQ * HD;
    const unsigned short* __restrict__ Vp = Vt + (size_t)b * 64 * 4096;
    const unsigned short* __restrict__ Qp = Qb + (size_t)b * SEQ * HD;

    short8 qfa0 = *(const short8*)(Qp + (size_t)(qa0 + lr) * HD +      lg * 8);
    short8 qfa1 = *(const short8*)(Qp + (size_t)(qa0 + lr) * HD + 32 + lg * 8);
    short8 qfb0 = *(const short8*)(Qp + (size_t)(qb0 + lr) * HD +      lg * 8);
    short8 qfb1 = *(const short8*)(Qp + (size_t)(qb0 + lr) * HD + 32 + lg * 8);

    f32x4 oA[4], oB[4];
    #pragma unroll
    for (int nt = 0; nt < 4; ++nt) { oA[nt] = f32x4{0.f,0.f,0.f,0.f}; oB[nt] = f32x4{0.f,0.f,0.f,0.f}; }
    float lrunA = 0.f, lrunB = 0.f;

    const int T   = 4 * (p + 1);                   // chunks covering [0, 256(p+1))
    const int sz  = (T + 7) >> 3;
    const int c0  = slice * sz;
    const int c1  = (c0 + sz < T) ? (c0 + sz) : T;
    const int nch = c1 - c0;
    const int swz = (lr & 7) << 3;

    auto stage = [&](int buf, int it) {
        const unsigned short* gk = Kp + (size_t)it * 64 * HD + w * 512 + lane * 8;
        const unsigned short* gv = Vp + (size_t)it * 4096 + w * 512 + lane * 8;
        __builtin_amdgcn_global_load_lds(
            (const __attribute__((address_space(1))) void*)gk,
            (__attribute__((address_space(3))) void*)(ldsK + buf * 4096 + w * 512), 16, 0, 0);
        __builtin_amdgcn_global_load_lds(
            (const __attribute__((address_space(1))) void*)gv,
            (__attribute__((address_space(3))) void*)(ldsV + buf * 4096 + w * 512), 16, 0, 0);
    };

    if (nch > 0) {
        stage(0, c0);
        if (nch > 1) stage(1, c0 + 1);
        for (int i = 0; i < nch; ++i) {
            if (i + 2 < nch) stage((i + 2) % 3, c0 + i + 2);
            if (i + 2 < nch)      asm volatile("s_waitcnt vmcnt(4)" ::: "memory");
            else if (i + 1 < nch) asm volatile("s_waitcnt vmcnt(2)" ::: "memory");
            else                  asm volatile("s_waitcnt vmcnt(0)" ::: "memory");
            __builtin_amdgcn_sched_barrier(0);
            __builtin_amdgcn_s_barrier();

            const int kvb = (c0 + i) * 64;
            const int bufo = (i % 3) * 4096;

            // ---- K fragments once, shared by both tiles
            short8 ka0 = *(const short8*)&ldsK[bufo + (0 * 16 + lr) * 64 + ((lg * 8)      ^ swz)];
            short8 kb0 = *(const short8*)&ldsK[bufo + (0 * 16 + lr) * 64 + ((lg * 8 + 32) ^ swz)];
            short8 ka1 = *(const short8*)&ldsK[bufo + (1 * 16 + lr) * 64 + ((lg * 8)      ^ swz)];
            short8 kb1 = *(const short8*)&ldsK[bufo + (1 * 16 + lr) * 64 + ((lg * 8 + 32) ^ swz)];
            short8 ka2 = *(const short8*)&ldsK[bufo + (2 * 16 + lr) * 64 + ((lg * 8)      ^ swz)];
            short8 kb2 = *(const short8*)&ldsK[bufo + (2 * 16 + lr) * 64 + ((lg * 8 + 32) ^ swz)];
            short8 ka3 = *(const short8*)&ldsK[bufo + (3 * 16 + lr) * 64 + ((lg * 8)      ^ swz)];
            short8 kb3 = *(const short8*)&ldsK[bufo + (3 * 16 + lr) * 64 + ((lg * 8 + 32) ^ swz)];

            short8 pbaA, pbbA, pbaB, pbbB;
            bool doA = (kvb <= qa0 + 15);
            bool doB = (kvb <= qb0 + 15);

            if (doA) {   // ---- tile A: QK + softmax -> pbaA/pbbA
                f32x4 s0 = f32x4{0.f,0.f,0.f,0.f}, s1 = f32x4{0.f,0.f,0.f,0.f};
                f32x4 s2 = f32x4{0.f,0.f,0.f,0.f}, s3 = f32x4{0.f,0.f,0.f,0.f};
                s0 = __builtin_amdgcn_mfma_f32_16x16x32_bf16(ka0, qfa0, s0, 0, 0, 0);
                s0 = __builtin_amdgcn_mfma_f32_16x16x32_bf16(kb0, qfa1, s0, 0, 0, 0);
                s1 = __builtin_amdgcn_mfma_f32_16x16x32_bf16(ka1, qfa0, s1, 0, 0, 0);
                s1 = __builtin_amdgcn_mfma_f32_16x16x32_bf16(kb1, qfa1, s1, 0, 0, 0);
                s2 = __builtin_amdgcn_mfma_f32_16x16x32_bf16(ka2, qfa0, s2, 0, 0, 0);
                s2 = __builtin_amdgcn_mfma_f32_16x16x32_bf16(kb2, qfa1, s2, 0, 0, 0);
                s3 = __builtin_amdgcn_mfma_f32_16x16x32_bf16(ka3, qfa0, s3, 0, 0, 0);
                s3 = __builtin_amdgcn_mfma_f32_16x16x32_bf16(kb3, qfa1, s3, 0, 0, 0);
                if (kvb + 63 > qa0) {
                    const int qg = qa0 + lr;
                    #pragma unroll
                    for (int r = 0; r < 4; ++r) {
                        int ky = kvb + lg * 4 + r;
                        if (ky      > qg) s0[r] = -1e30f;
                        if (ky + 16 > qg) s1[r] = -1e30f;
                        if (ky + 32 > qg) s2[r] = -1e30f;
                        if (ky + 48 > qg) s3[r] = -1e30f;
                    }
                }
                float p0[4], p1[4], p2[4], p3[4];
                #pragma unroll
                for (int r = 0; r < 4; ++r) {
                    p0[r] = exp2f(s0[r]); p1[r] = exp2f(s1[r]);
                    p2[r] = exp2f(s2[r]); p3[r] = exp2f(s3[r]);
                }
                lrunA += ((p0[0]+p0[1])+(p0[2]+p0[3])) + ((p1[0]+p1[1])+(p1[2]+p1[3]))
                       + ((p2[0]+p2[1])+(p2[2]+p2[3])) + ((p3[0]+p3[1])+(p3[2]+p3[3]));
                uint4v ua, ub;
                asm("v_cvt_pk_bf16_f32 %0, %1, %2" : "=v"(ua[0]) : "v"(p0[0]), "v"(p0[1]));
                asm("v_cvt_pk_bf16_f32 %0, %1, %2" : "=v"(ua[1]) : "v"(p0[2]), "v"(p0[3]));
                asm("v_cvt_pk_bf16_f32 %0, %1, %2" : "=v"(ua[2]) : "v"(p1[0]), "v"(p1[1]));
                asm("v_cvt_pk_bf16_f32 %0, %1, %2" : "=v"(ua[3]) : "v"(p1[2]), "v"(p1[3]));
                asm("v_cvt_pk_bf16_f32 %0, %1, %2" : "=v"(ub[0]) : "v"(p2[0]), "v"(p2[1]));
                asm("v_cvt_pk_bf16_f32 %0, %1, %2" : "=v"(ub[1]) : "v"(p2[2]), "v"(p2[3]));
                asm("v_cvt_pk_bf16_f32 %0, %1, %2" : "=v"(ub[2]) : "v"(p3[0]), "v"(p3[1]));
                asm("v_cvt_pk_bf16_f32 %0, %1, %2" : "=v"(ub[3]) : "v"(p3[2]), "v"(p3[3]));
                pbaA = *(short8*)&ua;  pbbA = *(short8*)&ub;
            }
            if (doB) {   // ---- tile B: QK + softmax -> pbaB/pbbB
                f32x4 s0 = f32x4{0.f,0.f,0.f,0.f}, s1 = f32x4{0.f,0.f,0.f,0.f};
                f32x4 s2 = f32x4{0.f,0.f,0.f,0.f}, s3 = f32x4{0.f,0.f,0.f,0.f};
                s0 = __builtin_amdgcn_mfma_f32_16x16x32_bf16(ka0, qfb0, s0, 0, 0, 0);
                s0 = __builtin_amdgcn_mfma_f32_16x16x32_bf16(kb0, qfb1, s0, 0, 0, 0);
                s1 = __builtin_amdgcn_mfma_f32_16x16x32_bf16(ka1, qfb0, s1, 0, 0, 0);
                s1 = __builtin_amdgcn_mfma_f32_16x16x32_bf16(kb1, qfb1, s1, 0, 0, 0);
                s2 = __builtin_amdgcn_mfma_f32_16x16x32_bf16(ka2, qfb0, s2, 0, 0, 0);
                s2 = __builtin_amdgcn_mfma_f32_16x16x32_bf16(kb2, qfb1, s2, 0, 0, 0);
                s3 = __builtin_amdgcn_mfma_f32_16x16x32_bf16(ka3, qfb0, s3, 0, 0, 0);
                s3 = __builtin_amdgcn_mfma_f32_16x16x32_bf16(kb3, qfb1, s3, 0, 0, 0);
                if (kvb + 63 > qb0) {
                    const int qg = qb0 + lr;
                    #pragma unroll
                    for (int r = 0; r < 4; ++r) {
                        int ky = kvb + lg * 4 + r;
                        if (ky      > qg) s0[r] = -1e30f;
                        if (ky + 16 > qg) s1[r] = -1e30f;
                        if (ky + 32 > qg) s2[r] = -1e30f;
                        if (ky + 48 > qg) s3[r] = -1e30f;
                    }
                }
                float p0[4], p1[4], p2[4], p3[4];
                #pragma unroll
                for (int r = 0; r < 4; ++r) {
                    p0[r] = exp2f(s0[r]); p1[r] = exp2f(s1[r]);
                    p2[r] = exp2f(s2[r]); p3[r] = exp2f(s3[r]);
                }
                lrunB += ((p0[0]+p0[1])+(p0[2]+p0[3])) + ((p1[0]+p1[1])+(p1[2]+p1[3]))
                       + ((p2[0]+p2[1])+(p2[2]+p2[3])) + ((p3[0]+p3[1])+(p3[2]+p3[3]));
                uint4v ua, ub;
                asm("v_cvt_pk_bf16_f32 %0, %1, %2" : "=v"(ua[0]) : "v"(p0[0]), "v"(p0[1]));
                asm("v_cvt_pk_bf16_f32 %0, %1, %2" : "=v"(ua[1]) : "v"(p0[2]), "v"(p0[3]));
                asm("v_cvt_pk_bf16_f32 %0, %1, %2" : "=v"(ua[2]) : "v"(p1[0]), "v"(p1[1]));
                asm("v_cvt_pk_bf16_f32 %0, %1, %2" : "=v"(ua[3]) : "v"(p1[2]), "v"(p1[3]));
                asm("v_cvt_pk_bf16_f32 %0, %1, %2" : "=v"(ub[0]) : "v"(p2[0]), "v"(p2[1]));
                asm("v_cvt_pk_bf16_f32 %0, %1, %2" : "=v"(ub[1]) : "v"(p2[2]), "v"(p2[3]));
                asm("v_cvt_pk_bf16_f32 %0, %1, %2" : "=v"(ub[2]) : "v"(p3[0]), "v"(p3[1]));
                asm("v_cvt_pk_bf16_f32 %0, %1, %2" : "=v"(ub[3]) : "v"(p3[2]), "v"(p3[3]));
                pbaB = *(short8*)&ua;  pbbB = *(short8*)&ub;
            }

            // ---- V fragments in two halves; PV for both tiles
            {
                short8 va0 = *(const short8*)&ldsV[bufo + (0 * 16 + lr) * 64 + ((lg * 8) ^ swz)];
                short8 va1 = *(const short8*)&ldsV[bufo + (1 * 16 + lr) * 64 + ((lg * 8) ^ swz)];
                short8 va2 = *(const short8*)&ldsV[bufo + (2 * 16 + lr) * 64 + ((lg * 8) ^ swz)];
                short8 va3 = *(const short8*)&ldsV[bufo + (3 * 16 + lr) * 64 + ((lg * 8) ^ swz)];
                if (doA) {
                    oA[0] = __builtin_amdgcn_mfma_f32_16x16x32_bf16(va0, pbaA, oA[0], 0, 0, 0);
                    oA[1] = __builtin_amdgcn_mfma_f32_16x16x32_bf16(va1, pbaA, oA[1], 0, 0, 0);
                    oA[2] = __builtin_amdgcn_mfma_f32_16x16x32_bf16(va2, pbaA, oA[2], 0, 0, 0);
                    oA[3] = __builtin_amdgcn_mfma_f32_16x16x32_bf16(va3, pbaA, oA[3], 0, 0, 0);
                }
                if (doB) {
                    oB[0] = __builtin_amdgcn_mfma_f32_16x16x32_bf16(va0, pbaB, oB[0], 0, 0, 0);
                    oB[1] = __builtin_amdgcn_mfma_f32_16x16x32_bf16(va1, pbaB, oB[1], 0, 0, 0);
                    oB[2] = __builtin_amdgcn_mfma_f32_16x16x32_bf16(va2, pbaB, oB[2], 0, 0, 0);
                    oB[3] = __builtin_amdgcn_mfma_f32_16x16x32_bf16(va3, pbaB, oB[3], 0, 0, 0);
                }
            }
            {
                short8 vb0 = *(const short8*)&ldsV[bufo + (0 * 16 + lr) * 64 + ((lg * 8 + 32) ^ swz)];
                short8 vb1 = *(const short8*)&ldsV[bufo + (1 * 16 + lr) * 64 + ((lg * 8 + 32) ^ swz)];
                short8 vb2 = *(const short8*)&ldsV[bufo + (2 * 16 + lr) * 64 + ((lg * 8 + 32) ^ swz)];
                short8 vb3 = *(const short8*)&ldsV[bufo + (3 * 16 + lr) * 64 + ((lg * 8 + 32) ^ swz)];
                if (doA) {
                    oA[0] = __builtin_amdgcn_mfma_f32_16x16x32_bf16(vb0, pbbA, oA[0], 0, 0, 0);
                    oA[1] = __builtin_amdgcn_mfma_f32_16x16x32_bf16(vb1, pbbA, oA[1], 0, 0, 0);
                    oA[2] = __builtin_amdgcn_mfma_f32_16x16x32_bf16(vb2, pbbA, oA[2], 0, 0, 0);
                    oA[3] = __builtin_amdgcn_mfma_f32_16x16x32_bf16(vb3, pbbA, oA[3], 0, 0, 0);
                }
                if (doB) {
                    oB[0] = __builtin_amdgcn_mfma_f32_16x16x32_bf16(vb0, pbbB, oB[0], 0, 0, 0);
                    oB[1] = __builtin_amdgcn_mfma_f32_16x16x32_bf16(vb1, pbbB, oB[1], 0, 0, 0);
                    oB[2] = __builtin_amdgcn_mfma_f32_16x16x32_bf16(vb2, pbbB, oB[2], 0, 0, 0);
                    oB[3] = __builtin_amdgcn_mfma_f32_16x16x32_bf16(vb3, pbbB, oB[3], 0, 0, 0);
                }
            }
            __builtin_amdgcn_s_barrier();   // readers of buf i%3 done before reuse
        }
    }

    // ---- per-q l across lane groups (exact: all terms share m=0)
    lrunA += __shfl_xor(lrunA, 16);
    lrunA += __shfl_xor(lrunA, 32);
    lrunB += __shfl_xor(lrunB, 16);
    lrunB += __shfl_xor(lrunB, 32);

    // ---- write slice partials (both tiles); layout part[(slice*4+b)*4096 + q][64]
    {
        const size_t prowA = ((size_t)slice * 4 + b) * 4096 + qa0 + lr;
        float* po = part_o + prowA * 64;
        #pragma unroll
        for (int nt = 0; nt < 4; ++nt)
            *(f32x4*)(po + nt * 16 + lg * 4) = oA[nt];
        if (lg == 0) part_l[prowA] = lrunA;
    }
    {
        const size_t prowB = ((size_t)slice * 4 + b) * 4096 + qb0 + lr;
        float* po = part_o + prowB * 64;
        #pragma unroll
        for (int nt = 0; nt < 4; ++nt)
            *(f32x4*)(po + nt * 16 + lg * 4) = oB[nt];
        if (lg == 0) part_l[prowB] = lrunB;
    }
}

// ---------------------------------------------------------------------------
// Merge: out = (sum_s o_s) / (sum_s l_s) over 8 slices.
// ---------------------------------------------------------------------------
__global__ __launch_bounds__(256) void merge_kernel(
        const float* __restrict__ part_o, const float* __restrict__ part_l,
        float* __restrict__ out) {
    int idx = blockIdx.x * 256 + threadIdx.x;    // 0..262143
    int d4  = (idx & 15) * 4;
    int row = idx >> 4;                           // 0..16383 == b*4096 + q
    f32x4 a = f32x4{0.f, 0.f, 0.f, 0.f};
    float L = 0.f;
    #pragma unroll
    for (int s = 0; s < 8; ++s) {
        f32x4 p = *(const f32x4*)(part_o + ((size_t)s * 16384 + row) * 64 + d4);
        a[0] += p[0]; a[1] += p[1]; a[2] += p[2]; a[3] += p[3];
        L += part_l[s * 16384 + row];
    }
    float inv = 1.0f / L;
    f32x4 r;
    r[0] = a[0] * inv;
    r[1] = a[1] * inv;
    r[2] = a[2] * inv;
    r[3] = a[3] * inv;
    *(f32x4*)(out + (size_t)row * 64 + d4) = r;
}

// ---------------------------------------------------------------------------
extern "C" void kernel_launch(void* const* d_in, const int* in_sizes, int n_in,
                              void* d_out, int out_size, void* d_ws, size_t ws_size,
                              hipStream_t stream) {
    const float* H  = (const float*)d_in[0];
    const float* Wq = (const float*)d_in[1];
    const float* Wk = (const float*)d_in[2];
    const float* Wv = (const float*)d_in[3];
    float* out = (float*)d_out;

    // ws (bf16): Qb[1M] | Kb[1M] | Vt[1M] | Wt[196608]
    //   then (f32): part_o[8*16384*64] (33.5 MB) | part_l[8*16384] (512 KB)
    unsigned short* Qb = (unsigned short*)d_ws;
    unsigned short* Kb = Qb + (size_t)NB * SEQ * HD;
    unsigned short* Vt = Kb + (size_t)NB * SEQ * HD;
    unsigned short* Wt = Vt + (size_t)NB * SEQ * HD;
    float* part_o = (float*)(Wt + 3 * 65536);
    float* part_l = part_o + (size_t)8 * 16384 * 64;

    wprep_kernel<<<768, 256, 0, stream>>>(Wq, Wk, Wv, Wt);
    qkv_kernel<<<NB * SEQ / 64, 512, 0, stream>>>(H, Wt, Qb, Kb, Vt);
    attn_kernel<<<512, 512, 0, stream>>>(Qb, Kb, Vt, part_o, part_l);
    merge_kernel<<<1024, 256, 0, stream>>>(part_o, part_l, out);
}

// Round 22
// 50.232 us; speedup vs baseline: 1.2891x; 1.2891x over previous
//
#include <hip/hip_runtime.h>
#include <hip/hip_bf16.h>
#include <stdint.h>

#define SEQ 4096
#define EMB 1024
#define HD  64
#define NB  4

typedef __attribute__((ext_vector_type(8))) short short8;   // 8 x bf16 (4 VGPRs)
typedef __attribute__((ext_vector_type(4))) float f32x4;
typedef __attribute__((ext_vector_type(4))) unsigned int uint4v;

// RNE float -> bf16 bits (no NaN inputs here)
static __device__ __forceinline__ unsigned short f2bf(float f) {
    unsigned int u = __float_as_uint(f);
    u += 0x7fffu + ((u >> 16) & 1u);
    return (unsigned short)(u >> 16);
}

// ---------------------------------------------------------------------------
// Prep: Wt[m][d][e] = bf16(W_m[e][d]),  m in {q,k,v}.  3*64*1024 elements.
// Wq is pre-scaled by log2(e)/sqrt(64) so attn needs no scale multiply.
// ---------------------------------------------------------------------------
__global__ __launch_bounds__(256) void wprep_kernel(
        const float* __restrict__ Wq, const float* __restrict__ Wk,
        const float* __restrict__ Wv, unsigned short* __restrict__ Wt) {
    int idx = blockIdx.x * 256 + threadIdx.x;       // < 3*65536
    int m = idx >> 16;
    int r = idx & 65535;
    int d = r >> 10;
    int e = r & 1023;
    const float* W = (m == 0) ? Wq : (m == 1) ? Wk : Wv;
    float v = W[e * HD + d];
    if (m == 0) v *= 0.18033688011111793f;          // log2(e)/sqrt(64)
    Wt[idx] = f2bf(v);
}

// ---------------------------------------------------------------------------
// QKV v3 — LDS-cooperative + 3-buffer counted-vmcnt pipeline (R18, proven).
// ---------------------------------------------------------------------------
__global__ __launch_bounds__(512, 4) void qkv_kernel(
        const float* __restrict__ H, const unsigned short* __restrict__ Wt,
        unsigned short* __restrict__ Qb, unsigned short* __restrict__ Kb,
        unsigned short* __restrict__ Vt) {
    __shared__ unsigned char smem[122880];           // 120 KB: 3 x (24KB W + 16KB H)
    unsigned short* ldsW = (unsigned short*)smem;            // [3][192][64] bf16
    float* ldsH = (float*)(smem + 3 * 24576);                // [3][64][64] f32
    float* ldsO = (float*)smem;                              // epilogue overlay [64][200]

    const int tid  = threadIdx.x;
    const int w    = tid >> 6;
    const int lane = tid & 63;
    const int lr = lane & 15, lg = lane >> 4;
    const int rt = w >> 1, ch = w & 1;
    const int rowbase = blockIdx.x * 64;

    f32x4 acc[6];
    #pragma unroll
    for (int nt = 0; nt < 6; ++nt) acc[nt] = f32x4{0.f, 0.f, 0.f, 0.f};

    auto stage = [&](int buf, int c) {
        const int kk0 = c * 64;
        #pragma unroll
        for (int ii = 0; ii < 3; ++ii) {
            int i = w * 3 + ii;
            int rowidx = 8 * i + (lane >> 3);            // 0..191  (m*64+d)
            int sb = (lane & 7) ^ (lane >> 3);           // src 16B-block ^ (row&7)
            const unsigned short* src = Wt + rowidx * EMB + kk0 + sb * 8;
            __builtin_amdgcn_global_load_lds(
                (const __attribute__((address_space(1))) void*)src,
                (__attribute__((address_space(3))) void*)(ldsW + buf * 12288 + i * 512 + lane * 8),
                16, 0, 0);
        }
        #pragma unroll
        for (int ii = 0; ii < 2; ++ii) {
            int i = w * 2 + ii;
            int rowidx = 4 * i + (lane >> 4);            // 0..63
            int key = rowidx & 7;
            int sb = (lane & 15) ^ key;                  // src 16B-block ^ (row&7)
            const float* src = H + (size_t)(rowbase + rowidx) * EMB + kk0 + sb * 4;
            __builtin_amdgcn_global_load_lds(
                (const __attribute__((address_space(1))) void*)src,
                (__attribute__((address_space(3))) void*)(ldsH + buf * 4096 + i * 256 + lane * 4),
                16, 0, 0);
        }
    };

    auto compute = [&](int buf) {
        const int hrow = rt * 16 + lr;
        const int hkey = lr & 7;
        #pragma unroll
        for (int ks = 0; ks < 2; ++ks) {
            int b0 = ks * 8 + lg * 2;
            f32x4 h0 = *(const f32x4*)(ldsH + buf * 4096 + hrow * 64 + ((b0 ^ hkey) * 4));
            f32x4 h1 = *(const f32x4*)(ldsH + buf * 4096 + hrow * 64 + (((b0 + 1) ^ hkey) * 4));
            uint4v ua;
            asm("v_cvt_pk_bf16_f32 %0, %1, %2" : "=v"(ua[0]) : "v"(h0[0]), "v"(h0[1]));
            asm("v_cvt_pk_bf16_f32 %0, %1, %2" : "=v"(ua[1]) : "v"(h0[2]), "v"(h0[3]));
            asm("v_cvt_pk_bf16_f32 %0, %1, %2" : "=v"(ua[2]) : "v"(h1[0]), "v"(h1[1]));
            asm("v_cvt_pk_bf16_f32 %0, %1, %2" : "=v"(ua[3]) : "v"(h1[2]), "v"(h1[3]));
            short8 af = *(short8*)&ua;
            #pragma unroll
            for (int nt = 0; nt < 6; ++nt) {
                int f = ch * 6 + nt;
                int row = f * 16 + lr;                   // (row&7) == lr&7 == hkey
                int blk = (ks * 4 + lg) ^ hkey;
                short8 bf_ = *(const short8*)(ldsW + buf * 12288 + row * 64 + blk * 8);
                acc[nt] = __builtin_amdgcn_mfma_f32_16x16x32_bf16(af, bf_, acc[nt], 0, 0, 0);
            }
        }
    };

    stage(0, 0);
    stage(1, 1);
    for (int c = 0; c < 16; ++c) {
        if (c + 2 < 16) stage((c + 2) % 3, c + 2);
        if (c <= 13)      asm volatile("s_waitcnt vmcnt(10)" ::: "memory");
        else if (c == 14) asm volatile("s_waitcnt vmcnt(5)"  ::: "memory");
        else              asm volatile("s_waitcnt vmcnt(0)"  ::: "memory");
        __builtin_amdgcn_sched_barrier(0);
        __builtin_amdgcn_s_barrier();
        compute(c % 3);
        __builtin_amdgcn_s_barrier();   // readers of buf c%3 done before reuse
    }

    #pragma unroll
    for (int nt = 0; nt < 6; ++nt)
        #pragma unroll
        for (int r = 0; r < 4; ++r)
            ldsO[(rt * 16 + lg * 4 + r) * 200 + ch * 96 + nt * 16 + lr] = acc[nt][r];
    __syncthreads();

    {   // Q and K: 512 threads, row = tid>>3 (0..63), 8 cols each
        const int row = tid >> 3;
        const int d0  = (tid & 7) * 8;
        const size_t grow = (size_t)(rowbase + row);
        short8 uq, uk;
        #pragma unroll
        for (int j = 0; j < 8; ++j) {
            uq[j] = (short)f2bf(ldsO[row * 200 + d0 + j]);
            uk[j] = (short)f2bf(ldsO[row * 200 + 64 + d0 + j]);
        }
        *(short8*)(Qb + grow * HD + d0) = uq;
        *(short8*)(Kb + grow * HD + (d0 ^ ((row & 7) << 3))) = uk;
    }
    {   // V: block covers exactly one 64-chunk; d = tid>>3, 4 u32 pairs each
        const int d  = tid >> 3;
        const int j  = tid & 7;
        const int b  = rowbase >> 12;
        const int ci = (rowbase & (SEQ - 1)) >> 6;
        unsigned short* vrow = Vt + (((size_t)b * 64 + ci) * 64 + d) * 64;
        const int dsw = (d & 7) << 3;
        #pragma unroll
        for (int k4 = 0; k4 < 4; ++k4) {
            int t0 = j * 2 + k4 * 16;            // even t in 0..62
            int tt = t0 & 31;
            int p0 = ((tt & 12) << 1) | (tt & 3) | ((tt & 16) >> 2);
            int e  = ((t0 & 32) | p0) ^ dsw;
            unsigned int val = (unsigned int)f2bf(ldsO[t0 * 200 + 128 + d])
                             | ((unsigned int)f2bf(ldsO[(t0 + 1) * 200 + 128 + d]) << 16);
            *(unsigned int*)(vrow + e) = val;
        }
    }
}

// ---------------------------------------------------------------------------
// Flash attention v4 (R19, measured best): 2-CHUNK BARRIER INTERVALS.
// 4-way K-slices with complementary-qb pairing; double-buffered chunk pairs;
// counted vmcnt (4 steady / 2 odd-tail / 0 final); m=0 softmax; exact merge.
// ---------------------------------------------------------------------------
__global__ __launch_bounds__(512, 2) void attn_kernel(
        const unsigned short* __restrict__ Qb, const unsigned short* __restrict__ Kb,
        const unsigned short* __restrict__ Vt,
        float* __restrict__ part_o, float* __restrict__ part_l) {
    __shared__ unsigned short ldsK[2 * 2 * 4096];  // 32 KB: [buf][pairslot][64x64]
    __shared__ unsigned short ldsV[2 * 2 * 4096];  // 32 KB
    const int tid  = threadIdx.x;
    const int w    = tid >> 6;
    const int lane = tid & 63;
    const int lr = lane & 15, lg = lane >> 4;

    const int bid   = blockIdx.x;
    const int b     = bid & 3;
    const int qbr   = (bid >> 2) & 31;
    const int slice = bid >> 7;                    // 0..3
    const int qb    = (slice >= 2) ? (31 - qbr) : qbr;   // complementary pairing
    const int qrow0 = qb * 128 + w * 16;           // this wave's 16 q-rows
    const int qwmax = qrow0 + 15;

    const unsigned short* __restrict__ Kp = Kb + (size_t)b * SEQ * HD;
    const unsigned short* __restrict__ Vp = Vt + (size_t)b * 64 * 4096;
    const unsigned short* __restrict__ Qp = Qb + ((size_t)b * SEQ + qrow0) * HD;

    short8 qf0 = *(const short8*)(Qp + lr * HD +      lg * 8);
    short8 qf1 = *(const short8*)(Qp + lr * HD + 32 + lg * 8);

    f32x4 o[4];
    #pragma unroll
    for (int nt = 0; nt < 4; ++nt) o[nt] = f32x4{0.f, 0.f, 0.f, 0.f};
    float lrun = 0.f;

    const int T  = 2 * (qb + 1);                   // total chunks for this q-block
    const int sz = (T + 3) >> 2;
    const int c0 = slice * sz;
    const int c1 = (c0 + sz < T) ? (c0 + sz) : T;
    const int nch = c1 - c0;                        // chunks for this block
    const int nin = (nch + 1) >> 1;                 // 2-chunk intervals
    const bool tail_odd = (nch & 1) != 0;
    const int swz = (lr & 7) << 3;

    // stage one interval (up to 2 chunks) into buffer `buf`
    auto stage_pair = [&](int buf, int j) {
        #pragma unroll
        for (int jj = 0; jj < 2; ++jj) {
            int ci = c0 + 2 * j + jj;
            if (ci < c1) {
                const unsigned short* gk = Kp + (size_t)ci * 64 * HD + w * 512 + lane * 8;
                const unsigned short* gv = Vp + (size_t)ci * 4096 + w * 512 + lane * 8;
                __builtin_amdgcn_global_load_lds(
                    (const __attribute__((address_space(1))) void*)gk,
                    (__attribute__((address_space(3))) void*)(ldsK + buf * 8192 + jj * 4096 + w * 512), 16, 0, 0);
                __builtin_amdgcn_global_load_lds(
                    (const __attribute__((address_space(1))) void*)gv,
                    (__attribute__((address_space(3))) void*)(ldsV + buf * 8192 + jj * 4096 + w * 512), 16, 0, 0);
            }
        }
    };

    if (nch > 0) {
        stage_pair(0, 0);
        for (int j = 0; j < nin; ++j) {
            if (j + 1 < nin) stage_pair((j + 1) & 1, j + 1);
            // wait for interval j's loads; remaining = loads of intervals beyond j
            if (j + 1 < nin) {
                if (tail_odd && (j + 2 == nin)) asm volatile("s_waitcnt vmcnt(2)" ::: "memory");
                else                            asm volatile("s_waitcnt vmcnt(4)" ::: "memory");
            } else {
                asm volatile("s_waitcnt vmcnt(0)" ::: "memory");
            }
            __builtin_amdgcn_sched_barrier(0);
            __builtin_amdgcn_s_barrier();

            #pragma unroll
            for (int jj = 0; jj < 2; ++jj) {
                const int ci = c0 + 2 * j + jj;
                if (ci < c1) {
                    const int kvb = ci * 64;
                    const int bufo = ((j & 1) * 2 + jj) * 4096;
                    if (kvb <= qwmax) {
                        f32x4 s0 = f32x4{0.f, 0.f, 0.f, 0.f};
                        f32x4 s1 = f32x4{0.f, 0.f, 0.f, 0.f};
                        f32x4 s2 = f32x4{0.f, 0.f, 0.f, 0.f};
                        f32x4 s3 = f32x4{0.f, 0.f, 0.f, 0.f};
                        {
                            short8 ka0 = *(const short8*)&ldsK[bufo + (0 * 16 + lr) * 64 + ((lg * 8)      ^ swz)];
                            short8 kb0 = *(const short8*)&ldsK[bufo + (0 * 16 + lr) * 64 + ((lg * 8 + 32) ^ swz)];
                            short8 ka1 = *(const short8*)&ldsK[bufo + (1 * 16 + lr) * 64 + ((lg * 8)      ^ swz)];
                            short8 kb1 = *(const short8*)&ldsK[bufo + (1 * 16 + lr) * 64 + ((lg * 8 + 32) ^ swz)];
                            short8 ka2 = *(const short8*)&ldsK[bufo + (2 * 16 + lr) * 64 + ((lg * 8)      ^ swz)];
                            short8 kb2 = *(const short8*)&ldsK[bufo + (2 * 16 + lr) * 64 + ((lg * 8 + 32) ^ swz)];
                            short8 ka3 = *(const short8*)&ldsK[bufo + (3 * 16 + lr) * 64 + ((lg * 8)      ^ swz)];
                            short8 kb3 = *(const short8*)&ldsK[bufo + (3 * 16 + lr) * 64 + ((lg * 8 + 32) ^ swz)];
                            s0 = __builtin_amdgcn_mfma_f32_16x16x32_bf16(ka0, qf0, s0, 0, 0, 0);
                            s0 = __builtin_amdgcn_mfma_f32_16x16x32_bf16(kb0, qf1, s0, 0, 0, 0);
                            s1 = __builtin_amdgcn_mfma_f32_16x16x32_bf16(ka1, qf0, s1, 0, 0, 0);
                            s1 = __builtin_amdgcn_mfma_f32_16x16x32_bf16(kb1, qf1, s1, 0, 0, 0);
                            s2 = __builtin_amdgcn_mfma_f32_16x16x32_bf16(ka2, qf0, s2, 0, 0, 0);
                            s2 = __builtin_amdgcn_mfma_f32_16x16x32_bf16(kb2, qf1, s2, 0, 0, 0);
                            s3 = __builtin_amdgcn_mfma_f32_16x16x32_bf16(ka3, qf0, s3, 0, 0, 0);
                            s3 = __builtin_amdgcn_mfma_f32_16x16x32_bf16(kb3, qf1, s3, 0, 0, 0);
                        }

                        if (kvb + 63 > qrow0) {          // mask if chunk passes FIRST row
                            const int qg = qrow0 + lr;
                            #pragma unroll
                            for (int r = 0; r < 4; ++r) {
                                int ky = kvb + lg * 4 + r;
                                if (ky      > qg) s0[r] = -1e30f;
                                if (ky + 16 > qg) s1[r] = -1e30f;
                                if (ky + 32 > qg) s2[r] = -1e30f;
                                if (ky + 48 > qg) s3[r] = -1e30f;
                            }
                        }

                        float p0[4], p1[4], p2[4], p3[4];
                        #pragma unroll
                        for (int r = 0; r < 4; ++r) {
                            p0[r] = exp2f(s0[r]);
                            p1[r] = exp2f(s1[r]);
                            p2[r] = exp2f(s2[r]);
                            p3[r] = exp2f(s3[r]);
                        }
                        lrun += ((p0[0] + p0[1]) + (p0[2] + p0[3])) + ((p1[0] + p1[1]) + (p1[2] + p1[3]))
                              + ((p2[0] + p2[1]) + (p2[2] + p2[3])) + ((p3[0] + p3[1]) + (p3[2] + p3[3]));

                        uint4v ua, ub;
                        asm("v_cvt_pk_bf16_f32 %0, %1, %2" : "=v"(ua[0]) : "v"(p0[0]), "v"(p0[1]));
                        asm("v_cvt_pk_bf16_f32 %0, %1, %2" : "=v"(ua[1]) : "v"(p0[2]), "v"(p0[3]));
                        asm("v_cvt_pk_bf16_f32 %0, %1, %2" : "=v"(ua[2]) : "v"(p1[0]), "v"(p1[1]));
                        asm("v_cvt_pk_bf16_f32 %0, %1, %2" : "=v"(ua[3]) : "v"(p1[2]), "v"(p1[3]));
                        asm("v_cvt_pk_bf16_f32 %0, %1, %2" : "=v"(ub[0]) : "v"(p2[0]), "v"(p2[1]));
                        asm("v_cvt_pk_bf16_f32 %0, %1, %2" : "=v"(ub[1]) : "v"(p2[2]), "v"(p2[3]));
                        asm("v_cvt_pk_bf16_f32 %0, %1, %2" : "=v"(ub[2]) : "v"(p3[0]), "v"(p3[1]));
                        asm("v_cvt_pk_bf16_f32 %0, %1, %2" : "=v"(ub[3]) : "v"(p3[2]), "v"(p3[3]));
                        short8 pba = *(short8*)&ua;      // keys kvb..kvb+31
                        short8 pbb = *(short8*)&ub;      // keys kvb+32..kvb+63

                        short8 va0 = *(const short8*)&ldsV[bufo + (0 * 16 + lr) * 64 + ((lg * 8)      ^ swz)];
                        short8 vb0 = *(const short8*)&ldsV[bufo + (0 * 16 + lr) * 64 + ((lg * 8 + 32) ^ swz)];
                        short8 va1 = *(const short8*)&ldsV[bufo + (1 * 16 + lr) * 64 + ((lg * 8)      ^ swz)];
                        short8 vb1 = *(const short8*)&ldsV[bufo + (1 * 16 + lr) * 64 + ((lg * 8 + 32) ^ swz)];
                        short8 va2 = *(const short8*)&ldsV[bufo + (2 * 16 + lr) * 64 + ((lg * 8)      ^ swz)];
                        short8 vb2 = *(const short8*)&ldsV[bufo + (2 * 16 + lr) * 64 + ((lg * 8 + 32) ^ swz)];
                        short8 va3 = *(const short8*)&ldsV[bufo + (3 * 16 + lr) * 64 + ((lg * 8)      ^ swz)];
                        short8 vb3 = *(const short8*)&ldsV[bufo + (3 * 16 + lr) * 64 + ((lg * 8 + 32) ^ swz)];
                        o[0] = __builtin_amdgcn_mfma_f32_16x16x32_bf16(va0, pba, o[0], 0, 0, 0);
                        o[1] = __builtin_amdgcn_mfma_f32_16x16x32_bf16(va1, pba, o[1], 0, 0, 0);
                        o[2] = __builtin_amdgcn_mfma_f32_16x16x32_bf16(va2, pba, o[2], 0, 0, 0);
                        o[3] = __builtin_amdgcn_mfma_f32_16x16x32_bf16(va3, pba, o[3], 0, 0, 0);
                        o[0] = __builtin_amdgcn_mfma_f32_16x16x32_bf16(vb0, pbb, o[0], 0, 0, 0);
                        o[1] = __builtin_amdgcn_mfma_f32_16x16x32_bf16(vb1, pbb, o[1], 0, 0, 0);
                        o[2] = __builtin_amdgcn_mfma_f32_16x16x32_bf16(vb2, pbb, o[2], 0, 0, 0);
                        o[3] = __builtin_amdgcn_mfma_f32_16x16x32_bf16(vb3, pbb, o[3], 0, 0, 0);
                    }
                }
            }
            __builtin_amdgcn_s_barrier();   // readers of buf j&1 done before reuse
        }
    }

    // ---- per-q l across lane groups (exact: all terms share m=0)
    lrun += __shfl_xor(lrun, 16);
    lrun += __shfl_xor(lrun, 32);

    // ---- write slice partials: o[nt][r] = O[q=lr][d = nt*16+lg*4+r]
    const size_t prow = (((size_t)slice * 4 + b) * 32 + qb) * 128 + w * 16 + lr;
    float* po = part_o + prow * 64;
    #pragma unroll
    for (int nt = 0; nt < 4; ++nt)
        *(f32x4*)(po + nt * 16 + lg * 4) = o[nt];
    if (lg == 0) part_l[prow] = lrun;
}

// ---------------------------------------------------------------------------
// Merge: out = (sum_s o_s) / (sum_s l_s) over 4 slices.
// prow(s,row) = s*16384 + row  (row = b*4096 + q).
// ---------------------------------------------------------------------------
__global__ __launch_bounds__(256) void merge_kernel(
        const float* __restrict__ part_o, const float* __restrict__ part_l,
        float* __restrict__ out) {
    int idx = blockIdx.x * 256 + threadIdx.x;    // 0..262143
    int d4  = (idx & 15) * 4;
    int row = idx >> 4;                           // 0..16383 == b*4096 + q
    f32x4 a = f32x4{0.f, 0.f, 0.f, 0.f};
    float L = 0.f;
    #pragma unroll
    for (int s = 0; s < 4; ++s) {
        f32x4 p = *(const f32x4*)(part_o + ((size_t)s * 16384 + row) * 64 + d4);
        a[0] += p[0]; a[1] += p[1]; a[2] += p[2]; a[3] += p[3];
        L += part_l[s * 16384 + row];
    }
    float inv = 1.0f / L;
    f32x4 r;
    r[0] = a[0] * inv;
    r[1] = a[1] * inv;
    r[2] = a[2] * inv;
    r[3] = a[3] * inv;
    *(f32x4*)(out + (size_t)row * 64 + d4) = r;
}

// ---------------------------------------------------------------------------
extern "C" void kernel_launch(void* const* d_in, const int* in_sizes, int n_in,
                              void* d_out, int out_size, void* d_ws, size_t ws_size,
                              hipStream_t stream) {
    const float* H  = (const float*)d_in[0];
    const float* Wq = (const float*)d_in[1];
    const float* Wk = (const float*)d_in[2];
    const float* Wv = (const float*)d_in[3];
    float* out = (float*)d_out;

    // ws (bf16): Qb[1M] | Kb[1M] | Vt[1M] | Wt[196608]
    //   then (f32): part_o[4*16384*64] (16 MB) | part_l[4*16384] (256 KB)
    unsigned short* Qb = (unsigned short*)d_ws;
    unsigned short* Kb = Qb + (size_t)NB * SEQ * HD;
    unsigned short* Vt = Kb + (size_t)NB * SEQ * HD;
    unsigned short* Wt = Vt + (size_t)NB * SEQ * HD;
    float* part_o = (float*)(Wt + 3 * 65536);
    float* part_l = part_o + (size_t)4 * 16384 * 64;

    wprep_kernel<<<768, 256, 0, stream>>>(Wq, Wk, Wv, Wt);
    qkv_kernel<<<NB * SEQ / 64, 512, 0, stream>>>(H, Wt, Qb, Kb, Vt);
    attn_kernel<<<512, 512, 0, stream>>>(Qb, Kb, Vt, part_o, part_l);
    merge_kernel<<<1024, 256, 0, stream>>>(part_o, part_l, out);
}